// Round 5
// baseline (1092.476 us; speedup 1.0000x reference)
//
#include <hip/hip_runtime.h>
#include <math.h>

#define NB   16
#define DIN  1024
#define TT   4096
#define DC   8
#define NK   1024
#define TILE 256
#define NTT  (TT/TILE)    // 16
#define DCH  256
#define NDC  (DIN/DCH)    // 4
#define OCH  128
#define NOC  (DIN/OCH)    // 8

// measurement round: in-kernel repeat factors (idempotent re-execution)
#define REP1 5
#define REP2 16
#define REP3 5

// d_out offsets (floats), in reference return order
#define OFF_CL  ((size_t)NB*DIN*TT)
#define OFF_CB  (OFF_CL + NB)
#define OFF_IDX (OFF_CB + NB)
#define OFF_ZE  (OFF_IDX + (size_t)NB*TT)

// opaque 0: defeats cross-rep CSE without changing addresses
__device__ __forceinline__ int opaque_zero() {
  int z = 0;
  asm volatile("" : "+v"(z));
  return z;
}

// ---------------- K1: in_proj partial sums (round-1 body, REP1 reps) ----------------
__global__ __launch_bounds__(256) void vq_k1_inproj(const float* __restrict__ z,
    const float* __restrict__ in_w, float* __restrict__ P)
{
  __shared__ float wt[DCH*DC];
  const int tid = threadIdx.x;
  const int tt = blockIdx.x, b = blockIdx.y, dc = blockIdx.z;
  const int dbase = dc*DCH;
  #pragma unroll
  for (int o = 0; o < DC; ++o)
    wt[tid*DC + o] = in_w[o*DIN + dbase + tid];
  __syncthreads();
  const int t = tt*TILE + tid;
  for (int rep = 0; rep < REP1; ++rep) {
    const float* zp = z + ((size_t)b*DIN + dbase)*TT + t + opaque_zero();
    float acc[DC];
    #pragma unroll
    for (int o = 0; o < DC; ++o) acc[o] = 0.f;
    #pragma unroll 8
    for (int d = 0; d < DCH; ++d) {
      const float v = zp[(size_t)d*TT];
      const float4 w0 = *(const float4*)&wt[d*DC];
      const float4 w1 = *(const float4*)&wt[d*DC+4];
      acc[0] = fmaf(v, w0.x, acc[0]);
      acc[1] = fmaf(v, w0.y, acc[1]);
      acc[2] = fmaf(v, w0.z, acc[2]);
      acc[3] = fmaf(v, w0.w, acc[3]);
      acc[4] = fmaf(v, w1.x, acc[4]);
      acc[5] = fmaf(v, w1.y, acc[5]);
      acc[6] = fmaf(v, w1.z, acc[6]);
      acc[7] = fmaf(v, w1.w, acc[7]);
    }
    float* pp = P + ((size_t)(dc*NB + b)*DC)*TT + t;
    #pragma unroll
    for (int o = 0; o < DC; ++o) pp[(size_t)o*TT] = acc[o];
  }
}

// ---------------- K2: combine + LDS-codebook VQ + rotation (round-1 body, REP2 reps) ----------------
__global__ __launch_bounds__(256) void vq_k2_search(const float* __restrict__ P,
    const float* __restrict__ in_b, const float* __restrict__ cbk,
    float* __restrict__ dout, float* __restrict__ zq, float* __restrict__ lpart)
{
  __shared__ float cn[NK*DC];   // 32 KB normalized codebook
  __shared__ float cn2[NK];     // 4 KB
  __shared__ float lred[256];
  const int tid = threadIdx.x;
  const int tt = blockIdx.x, b = blockIdx.y;

  for (int k = tid; k < NK; k += 256) {
    float c[DC];
    const float4 c0 = *(const float4*)&cbk[k*DC];
    const float4 c1 = *(const float4*)&cbk[k*DC+4];
    c[0]=c0.x; c[1]=c0.y; c[2]=c0.z; c[3]=c0.w;
    c[4]=c1.x; c[5]=c1.y; c[6]=c1.z; c[7]=c1.w;
    float ss = 0.f;
    #pragma unroll
    for (int i = 0; i < DC; ++i) ss = fmaf(c[i], c[i], ss);
    const float den = fmaxf(sqrtf(ss), 1e-12f);
    float s2 = 0.f;
    #pragma unroll
    for (int i = 0; i < DC; ++i) { const float v = c[i]/den; cn[k*DC+i] = v; s2 = fmaf(v, v, s2); }
    cn2[k] = s2;
  }
  __syncthreads();

  const int t = tt*TILE + tid;
  for (int rep = 0; rep < REP2; ++rep) {
    float e[DC];
    {
      const float* pp = P + ((size_t)b*DC)*TT + t + opaque_zero();
      const size_t cs = (size_t)NB*DC*TT;
      #pragma unroll
      for (int o = 0; o < DC; ++o) {
        float s = pp[(size_t)o*TT];
        s += pp[cs   + (size_t)o*TT];
        s += pp[2*cs + (size_t)o*TT];
        s += pp[3*cs + (size_t)o*TT];
        e[o] = s + in_b[o];
      }
    }
    #pragma unroll
    for (int o = 0; o < DC; ++o)
      dout[OFF_ZE + ((size_t)b*DC + o)*TT + t] = e[o];

    float se = 0.f;
    #pragma unroll
    for (int i = 0; i < DC; ++i) se = fmaf(e[i], e[i], se);
    const float ne = sqrtf(se);
    const float dene = fmaxf(ne, 1e-12f);
    float en[DC];
    #pragma unroll
    for (int i = 0; i < DC; ++i) en[i] = e[i]/dene;
    float en2 = 0.f;
    #pragma unroll
    for (int i = 0; i < DC; ++i) en2 = fmaf(en[i], en[i], en2);

    float bestd = 3.4e38f; int bk = 0;
    #pragma unroll 4
    for (int k = 0; k < NK; ++k) {
      const float4 a0 = *(const float4*)&cn[k*DC];
      const float4 a1 = *(const float4*)&cn[k*DC+4];
      float dacc = en[0]*a0.x;
      dacc = fmaf(en[1], a0.y, dacc);
      dacc = fmaf(en[2], a0.z, dacc);
      dacc = fmaf(en[3], a0.w, dacc);
      dacc = fmaf(en[4], a1.x, dacc);
      dacc = fmaf(en[5], a1.y, dacc);
      dacc = fmaf(en[6], a1.z, dacc);
      dacc = fmaf(en[7], a1.w, dacc);
      const float dist = (en2 - 2.0f*dacc) + cn2[k];
      if (dist < bestd) { bestd = dist; bk = k; }
    }
    dout[OFF_IDX + (size_t)b*TT + t] = (float)bk;

    float q[DC];
    {
      const float4 q0 = *(const float4*)&cbk[bk*DC];
      const float4 q1 = *(const float4*)&cbk[bk*DC+4];
      q[0]=q0.x; q[1]=q0.y; q[2]=q0.z; q[3]=q0.w;
      q[4]=q1.x; q[5]=q1.y; q[6]=q1.z; q[7]=q1.w;
    }
    float cl = 0.f;
    #pragma unroll
    for (int i = 0; i < DC; ++i) { const float d = e[i]-q[i]; cl = fmaf(d, d, cl); }

    float sq = 0.f;
    #pragma unroll
    for (int i = 0; i < DC; ++i) sq = fmaf(q[i], q[i], sq);
    const float nq = sqrtf(sq);
    const float denq = fmaxf(nq, 1e-12f);
    float qn[DC], rr[DC];
    float sr = 0.f;
    #pragma unroll
    for (int i = 0; i < DC; ++i) { qn[i] = q[i]/denq; rr[i] = en[i]+qn[i]; sr = fmaf(rr[i], rr[i], sr); }
    const float denr = fmaxf(sqrtf(sr), 1e-12f);
    float r_[DC];
    float rdz = 0.f, edz = 0.f;
    #pragma unroll
    for (int i = 0; i < DC; ++i) { r_[i] = rr[i]/denr; rdz = fmaf(r_[i], e[i], rdz); edz = fmaf(en[i], e[i], edz); }
    const float scal = nq / fmaxf(ne, 1e-8f);
    #pragma unroll
    for (int i = 0; i < DC; ++i) {
      const float v = scal * ((e[i] - 2.0f*r_[i]*rdz) + 2.0f*qn[i]*edz);
      zq[((size_t)b*DC + i)*TT + t] = v;
    }

    lred[tid] = cl;
    __syncthreads();
    for (int s = 128; s > 0; s >>= 1) {
      if (tid < s) lred[tid] += lred[tid + s];
      __syncthreads();
    }
    if (tid == 0) lpart[b*NTT + tt] = lred[0];
    __syncthreads();
  }
}

// ---------------- K3: out_proj (round-1 body, REP3 reps) ----------------
__global__ __launch_bounds__(256) void vq_k3_outproj(const float* __restrict__ zq,
    const float* __restrict__ out_w, const float* __restrict__ out_b,
    float* __restrict__ dout)
{
  __shared__ float wo[OCH*DC];
  __shared__ float ob[OCH];
  const int tid = threadIdx.x;
  const int tt = blockIdx.x, b = blockIdx.y, oc = blockIdx.z;
  const int obase = oc*OCH;
  for (int i = tid; i < OCH*DC; i += 256) wo[i] = out_w[obase*DC + i];
  if (tid < OCH) ob[tid] = out_b[obase + tid];
  __syncthreads();
  const int t = tt*TILE + tid;
  for (int rep = 0; rep < REP3; ++rep) {
    const float* zp = zq + opaque_zero();
    float zr[DC];
    #pragma unroll
    for (int c = 0; c < DC; ++c) zr[c] = zp[((size_t)b*DC + c)*TT + t];
    float* op = dout + ((size_t)b*DIN + obase)*TT + t;
    #pragma unroll 4
    for (int o = 0; o < OCH; ++o) {
      const float4 w0 = *(const float4*)&wo[o*DC];
      const float4 w1 = *(const float4*)&wo[o*DC+4];
      float s = ob[o];
      s = fmaf(zr[0], w0.x, s);
      s = fmaf(zr[1], w0.y, s);
      s = fmaf(zr[2], w0.z, s);
      s = fmaf(zr[3], w0.w, s);
      s = fmaf(zr[4], w1.x, s);
      s = fmaf(zr[5], w1.y, s);
      s = fmaf(zr[6], w1.z, s);
      s = fmaf(zr[7], w1.w, s);
      op[(size_t)o*TT] = s;
    }
  }
}

// ---------------- K4: loss finalize ----------------
__global__ void vq_k4_loss(const float* __restrict__ lpart, float* __restrict__ dout)
{
  const int b = threadIdx.x;
  if (b < NB) {
    float s = 0.f;
    for (int j = 0; j < NTT; ++j) s += lpart[b*NTT + j];
    const float v = s / (float)(TT*DC);
    dout[OFF_CL + b] = v;
    dout[OFF_CB + b] = v;
  }
}

extern "C" void kernel_launch(void* const* d_in, const int* in_sizes, int n_in,
                              void* d_out, int out_size, void* d_ws, size_t ws_size,
                              hipStream_t stream) {
  const float* z     = (const float*)d_in[0];
  const float* in_w  = (const float*)d_in[1];
  const float* in_b  = (const float*)d_in[2];
  const float* out_w = (const float*)d_in[3];
  const float* out_b = (const float*)d_in[4];
  const float* cbk   = (const float*)d_in[5];
  float* out = (float*)d_out;
  float* ws  = (float*)d_ws;

  float* P  = ws;                                   // 2,097,152 floats
  float* ZQ = P  + (size_t)NDC*NB*DC*TT;            //   524,288 floats
  float* LP = ZQ + (size_t)NB*DC*TT;                //       256 floats

  vq_k1_inproj <<<dim3(NTT, NB, NDC), 256, 0, stream>>>(z, in_w, P);
  vq_k2_search <<<dim3(NTT, NB),      256, 0, stream>>>(P, in_b, cbk, out, ZQ, LP);
  vq_k3_outproj<<<dim3(NTT, NB, NOC), 256, 0, stream>>>(ZQ, out_w, out_b, out);
  vq_k4_loss   <<<1, 256, 0, stream>>>(LP, out);
}

// Round 6
// 206.575 us; speedup vs baseline: 5.2885x; 5.2885x over previous
//
#include <hip/hip_runtime.h>
#include <math.h>

#define NB   16
#define DIN  1024
#define TT   4096
#define DC   8
#define NK   1024
#define NTT  16              // 256-wide t-tiles for K2a/K2c/loss

// K1 variant A (8 chunks, float2)
#define DCH8 128
#define NCH8 8
// K1 variant B (round-1 proven: 4 chunks, scalar)
#define DCH4 256
#define NCH4 4
// K2b: k-split x4, 4 t/thread
#define KSP    4
#define KCODES (NK/KSP)      // 256
#define T2TILE 1024          // 256 threads * 4 t
// K3: o-chunk 64, 4 t/thread (float4)
#define OCH  64
#define NOC  (DIN/OCH)       // 16

// d_out offsets (floats), in reference return order
#define OFF_CL  ((size_t)NB*DIN*TT)
#define OFF_CB  (OFF_CL + NB)
#define OFF_IDX (OFF_CB + NB)
#define OFF_ZE  (OFF_IDX + (size_t)NB*TT)

// ---------------- K1-A: in_proj partials, 8 chunks, float2 loads ----------------
__global__ __launch_bounds__(256) void vq_k1_ch8(const float* __restrict__ z,
    const float* __restrict__ in_w, float* __restrict__ P)
{
  __shared__ float wt[DCH8*DC];
  const int tid = threadIdx.x;
  const int tt = blockIdx.x, b = blockIdx.y, ch = blockIdx.z;
  const int dbase = ch*DCH8;
  if (tid < DCH8) {
    #pragma unroll
    for (int o = 0; o < DC; ++o)
      wt[tid*DC + o] = in_w[o*DIN + dbase + tid];
  }
  __syncthreads();
  const int t = tt*512 + tid*2;
  const float* zp = z + ((size_t)b*DIN + dbase)*TT + t;
  float ax[DC], ay[DC];
  #pragma unroll
  for (int o = 0; o < DC; ++o) { ax[o] = 0.f; ay[o] = 0.f; }
  #pragma unroll 8
  for (int d = 0; d < DCH8; ++d) {
    const float2 v = *(const float2*)&zp[(size_t)d*TT];
    const float4 w0 = *(const float4*)&wt[d*DC];
    const float4 w1 = *(const float4*)&wt[d*DC+4];
    ax[0] = fmaf(v.x, w0.x, ax[0]);  ay[0] = fmaf(v.y, w0.x, ay[0]);
    ax[1] = fmaf(v.x, w0.y, ax[1]);  ay[1] = fmaf(v.y, w0.y, ay[1]);
    ax[2] = fmaf(v.x, w0.z, ax[2]);  ay[2] = fmaf(v.y, w0.z, ay[2]);
    ax[3] = fmaf(v.x, w0.w, ax[3]);  ay[3] = fmaf(v.y, w0.w, ay[3]);
    ax[4] = fmaf(v.x, w1.x, ax[4]);  ay[4] = fmaf(v.y, w1.x, ay[4]);
    ax[5] = fmaf(v.x, w1.y, ax[5]);  ay[5] = fmaf(v.y, w1.y, ay[5]);
    ax[6] = fmaf(v.x, w1.z, ax[6]);  ay[6] = fmaf(v.y, w1.z, ay[6]);
    ax[7] = fmaf(v.x, w1.w, ax[7]);  ay[7] = fmaf(v.y, w1.w, ay[7]);
  }
  float* pp = P + ((size_t)(ch*NB + b)*DC)*TT + t;
  #pragma unroll
  for (int o = 0; o < DC; ++o)
    *(float2*)&pp[(size_t)o*TT] = make_float2(ax[o], ay[o]);
}

// ---------------- K1-B: round-1 proven (4 chunks, scalar) ----------------
__global__ __launch_bounds__(256) void vq_k1_ch4(const float* __restrict__ z,
    const float* __restrict__ in_w, float* __restrict__ P)
{
  __shared__ float wt[DCH4*DC];
  const int tid = threadIdx.x;
  const int tt = blockIdx.x, b = blockIdx.y, dc = blockIdx.z;
  const int dbase = dc*DCH4;
  #pragma unroll
  for (int o = 0; o < DC; ++o)
    wt[tid*DC + o] = in_w[o*DIN + dbase + tid];
  __syncthreads();
  const int t = tt*256 + tid;
  const float* zp = z + ((size_t)b*DIN + dbase)*TT + t;
  float acc[DC];
  #pragma unroll
  for (int o = 0; o < DC; ++o) acc[o] = 0.f;
  #pragma unroll 8
  for (int d = 0; d < DCH4; ++d) {
    const float v = zp[(size_t)d*TT];
    const float4 w0 = *(const float4*)&wt[d*DC];
    const float4 w1 = *(const float4*)&wt[d*DC+4];
    acc[0] = fmaf(v, w0.x, acc[0]);
    acc[1] = fmaf(v, w0.y, acc[1]);
    acc[2] = fmaf(v, w0.z, acc[2]);
    acc[3] = fmaf(v, w0.w, acc[3]);
    acc[4] = fmaf(v, w1.x, acc[4]);
    acc[5] = fmaf(v, w1.y, acc[5]);
    acc[6] = fmaf(v, w1.z, acc[6]);
    acc[7] = fmaf(v, w1.w, acc[7]);
  }
  float* pp = P + ((size_t)(dc*NB + b)*DC)*TT + t;
  #pragma unroll
  for (int o = 0; o < DC; ++o) pp[(size_t)o*TT] = acc[o];
}

// ---------------- K2a: combine partials + bias -> z_e (in d_out) ----------------
template<int CH>
__global__ __launch_bounds__(256) void vq_k2a(const float* __restrict__ P,
    const float* __restrict__ in_b, float* __restrict__ dout)
{
  const int tid = threadIdx.x;
  const int tt = blockIdx.x, b = blockIdx.y;
  const int t = tt*256 + tid;
  const float* pp = P + ((size_t)b*DC)*TT + t;
  const size_t cs = (size_t)NB*DC*TT;
  #pragma unroll
  for (int o = 0; o < DC; ++o) {
    float s = pp[(size_t)o*TT];
    #pragma unroll
    for (int c = 1; c < CH; ++c) s += pp[c*cs + (size_t)o*TT];
    dout[OFF_ZE + ((size_t)b*DC + o)*TT + t] = s + in_b[o];
  }
}

// ---------------- K2b: k-split codebook scan, 4 t/thread ----------------
__global__ __launch_bounds__(256) void vq_k2b(const float* __restrict__ cbk,
    const float* __restrict__ ze, float* __restrict__ cand)
{
  __shared__ float cns[KCODES*DC];   // 8 KB
  __shared__ float cn2s[KCODES];     // 1 KB
  const int tid = threadIdx.x;
  const int tb = blockIdx.x, b = blockIdx.y, kp = blockIdx.z;
  const int k0 = kp*KCODES;

  // stage + normalize this partition (identical chain to round-1 staging)
  {
    const int k = k0 + tid;
    float c[DC];
    const float4 c0 = *(const float4*)&cbk[k*DC];
    const float4 c1 = *(const float4*)&cbk[k*DC+4];
    c[0]=c0.x; c[1]=c0.y; c[2]=c0.z; c[3]=c0.w;
    c[4]=c1.x; c[5]=c1.y; c[6]=c1.z; c[7]=c1.w;
    float ss = 0.f;
    #pragma unroll
    for (int i = 0; i < DC; ++i) ss = fmaf(c[i], c[i], ss);
    const float den = fmaxf(sqrtf(ss), 1e-12f);
    float s2 = 0.f;
    #pragma unroll
    for (int i = 0; i < DC; ++i) { const float v = c[i]/den; cns[tid*DC+i] = v; s2 = fmaf(v, v, s2); }
    cn2s[tid] = s2;
  }
  __syncthreads();

  const int t0 = tb*T2TILE + tid*4;
  // load e for 4 t's (float4 over t per channel), normalize each (round-1 chain)
  float en[4][DC], en2[4];
  #pragma unroll
  for (int o = 0; o < DC; ++o) {
    const float4 v = *(const float4*)&ze[((size_t)b*DC + o)*TT + t0];
    en[0][o]=v.x; en[1][o]=v.y; en[2][o]=v.z; en[3][o]=v.w;
  }
  #pragma unroll
  for (int j = 0; j < 4; ++j) {
    float se = 0.f;
    #pragma unroll
    for (int i = 0; i < DC; ++i) se = fmaf(en[j][i], en[j][i], se);
    const float dene = fmaxf(sqrtf(se), 1e-12f);
    float s2 = 0.f;
    #pragma unroll
    for (int i = 0; i < DC; ++i) { en[j][i] /= dene; s2 = fmaf(en[j][i], en[j][i], s2); }
    en2[j] = s2;
  }

  float bd[4]; int bk[4];
  #pragma unroll
  for (int j = 0; j < 4; ++j) { bd[j] = 3.4e38f; bk[j] = k0; }
  #pragma unroll 2
  for (int k = 0; k < KCODES; ++k) {
    const float4 a0 = *(const float4*)&cns[k*DC];
    const float4 a1 = *(const float4*)&cns[k*DC+4];
    const float c2 = cn2s[k];
    #pragma unroll
    for (int j = 0; j < 4; ++j) {
      float dacc = en[j][0]*a0.x;
      dacc = fmaf(en[j][1], a0.y, dacc);
      dacc = fmaf(en[j][2], a0.z, dacc);
      dacc = fmaf(en[j][3], a0.w, dacc);
      dacc = fmaf(en[j][4], a1.x, dacc);
      dacc = fmaf(en[j][5], a1.y, dacc);
      dacc = fmaf(en[j][6], a1.z, dacc);
      dacc = fmaf(en[j][7], a1.w, dacc);
      const float dist = (en2[j] - 2.0f*dacc) + c2;   // round-1 exact chain
      if (dist < bd[j]) { bd[j] = dist; bk[j] = k0 + k; }
    }
  }
  // 4 consecutive (dist, k) pairs -> two float4 stores (32B contiguous)
  float* cp = cand + ((size_t)(kp*NB + b)*TT + t0)*2;
  *(float4*)&cp[0] = make_float4(bd[0], __int_as_float(bk[0]), bd[1], __int_as_float(bk[1]));
  *(float4*)&cp[4] = make_float4(bd[2], __int_as_float(bk[2]), bd[3], __int_as_float(bk[3]));
}

// ---------------- K2c: merge partitions + rotation trick + loss ----------------
__global__ __launch_bounds__(256) void vq_k2c(const float* __restrict__ cand,
    const float* __restrict__ ze, const float* __restrict__ cbk,
    float* __restrict__ dout, float* __restrict__ zq, float* __restrict__ lpart)
{
  __shared__ float lred[256];
  const int tid = threadIdx.x;
  const int tt = blockIdx.x, b = blockIdx.y;
  const int t = tt*256 + tid;

  // merge in ascending-partition order, strict < => global first occurrence
  float bd; int bk;
  {
    const float2 c0 = *(const float2*)&cand[((size_t)(0*NB + b)*TT + t)*2];
    bd = c0.x; bk = __float_as_int(c0.y);
    #pragma unroll
    for (int kp = 1; kp < KSP; ++kp) {
      const float2 c = *(const float2*)&cand[((size_t)(kp*NB + b)*TT + t)*2];
      if (c.x < bd) { bd = c.x; bk = __float_as_int(c.y); }
    }
  }
  dout[OFF_IDX + (size_t)b*TT + t] = (float)bk;

  // e from z_e, recompute norms (round-1 chains)
  float e[DC], en[DC];
  #pragma unroll
  for (int o = 0; o < DC; ++o) e[o] = ze[((size_t)b*DC + o)*TT + t];
  float se = 0.f;
  #pragma unroll
  for (int i = 0; i < DC; ++i) se = fmaf(e[i], e[i], se);
  const float ne = sqrtf(se);
  const float dene = fmaxf(ne, 1e-12f);
  #pragma unroll
  for (int i = 0; i < DC; ++i) en[i] = e[i]/dene;

  float q[DC];
  {
    const float4 q0 = *(const float4*)&cbk[bk*DC];
    const float4 q1 = *(const float4*)&cbk[bk*DC+4];
    q[0]=q0.x; q[1]=q0.y; q[2]=q0.z; q[3]=q0.w;
    q[4]=q1.x; q[5]=q1.y; q[6]=q1.z; q[7]=q1.w;
  }
  float cl = 0.f;
  #pragma unroll
  for (int i = 0; i < DC; ++i) { const float d = e[i]-q[i]; cl = fmaf(d, d, cl); }

  float sq = 0.f;
  #pragma unroll
  for (int i = 0; i < DC; ++i) sq = fmaf(q[i], q[i], sq);
  const float nq = sqrtf(sq);
  const float denq = fmaxf(nq, 1e-12f);
  float qn[DC], rr[DC];
  float sr = 0.f;
  #pragma unroll
  for (int i = 0; i < DC; ++i) { qn[i] = q[i]/denq; rr[i] = en[i]+qn[i]; sr = fmaf(rr[i], rr[i], sr); }
  const float denr = fmaxf(sqrtf(sr), 1e-12f);
  float r_[DC];
  float rdz = 0.f, edz = 0.f;
  #pragma unroll
  for (int i = 0; i < DC; ++i) { r_[i] = rr[i]/denr; rdz = fmaf(r_[i], e[i], rdz); edz = fmaf(en[i], e[i], edz); }
  const float scal = nq / fmaxf(ne, 1e-8f);
  #pragma unroll
  for (int i = 0; i < DC; ++i) {
    const float v = scal * ((e[i] - 2.0f*r_[i]*rdz) + 2.0f*qn[i]*edz);
    zq[((size_t)b*DC + i)*TT + t] = v;
  }

  lred[tid] = cl;
  __syncthreads();
  for (int s = 128; s > 0; s >>= 1) {
    if (tid < s) lred[tid] += lred[tid + s];
    __syncthreads();
  }
  if (tid == 0) lpart[b*NTT + tt] = lred[0];
}

// ---------------- K3: out_proj, o-chunk 64, float4 stores ----------------
__global__ __launch_bounds__(256) void vq_k3_outproj(const float* __restrict__ zq,
    const float* __restrict__ out_w, const float* __restrict__ out_b,
    float* __restrict__ dout)
{
  __shared__ float wo[OCH*DC];   // 512 floats
  __shared__ float ob[OCH];
  const int tid = threadIdx.x;
  const int tb = blockIdx.x, b = blockIdx.y, oc = blockIdx.z;
  const int obase = oc*OCH;
  if (tid < 128) *(float4*)&wo[tid*4] = *(const float4*)&out_w[obase*DC + tid*4];
  if (tid < OCH) ob[tid] = out_b[obase + tid];
  __syncthreads();
  const int t = tb*1024 + tid*4;
  float z0[DC], z1[DC], z2[DC], z3[DC];
  #pragma unroll
  for (int c = 0; c < DC; ++c) {
    const float4 v = *(const float4*)&zq[((size_t)b*DC + c)*TT + t];
    z0[c]=v.x; z1[c]=v.y; z2[c]=v.z; z3[c]=v.w;
  }
  float* op = dout + ((size_t)b*DIN + obase)*TT + t;
  #pragma unroll 2
  for (int o = 0; o < OCH; ++o) {
    const float4 w0 = *(const float4*)&wo[o*DC];
    const float4 w1 = *(const float4*)&wo[o*DC+4];
    const float bv = ob[o];
    float s0 = bv, s1 = bv, s2 = bv, s3 = bv;
    s0 = fmaf(z0[0], w0.x, s0); s1 = fmaf(z1[0], w0.x, s1); s2 = fmaf(z2[0], w0.x, s2); s3 = fmaf(z3[0], w0.x, s3);
    s0 = fmaf(z0[1], w0.y, s0); s1 = fmaf(z1[1], w0.y, s1); s2 = fmaf(z2[1], w0.y, s2); s3 = fmaf(z3[1], w0.y, s3);
    s0 = fmaf(z0[2], w0.z, s0); s1 = fmaf(z1[2], w0.z, s1); s2 = fmaf(z2[2], w0.z, s2); s3 = fmaf(z3[2], w0.z, s3);
    s0 = fmaf(z0[3], w0.w, s0); s1 = fmaf(z1[3], w0.w, s1); s2 = fmaf(z2[3], w0.w, s2); s3 = fmaf(z3[3], w0.w, s3);
    s0 = fmaf(z0[4], w1.x, s0); s1 = fmaf(z1[4], w1.x, s1); s2 = fmaf(z2[4], w1.x, s2); s3 = fmaf(z3[4], w1.x, s3);
    s0 = fmaf(z0[5], w1.y, s0); s1 = fmaf(z1[5], w1.y, s1); s2 = fmaf(z2[5], w1.y, s2); s3 = fmaf(z3[5], w1.y, s3);
    s0 = fmaf(z0[6], w1.z, s0); s1 = fmaf(z1[6], w1.z, s1); s2 = fmaf(z2[6], w1.z, s2); s3 = fmaf(z3[6], w1.z, s3);
    s0 = fmaf(z0[7], w1.w, s0); s1 = fmaf(z1[7], w1.w, s1); s2 = fmaf(z2[7], w1.w, s2); s3 = fmaf(z3[7], w1.w, s3);
    *(float4*)&op[(size_t)o*TT] = make_float4(s0, s1, s2, s3);
  }
}

// ---------------- K4: loss finalize ----------------
__global__ void vq_k4_loss(const float* __restrict__ lpart, float* __restrict__ dout)
{
  const int b = threadIdx.x;
  if (b < NB) {
    float s = 0.f;
    for (int j = 0; j < NTT; ++j) s += lpart[b*NTT + j];
    const float v = s / (float)(TT*DC);
    dout[OFF_CL + b] = v;
    dout[OFF_CB + b] = v;
  }
}

extern "C" void kernel_launch(void* const* d_in, const int* in_sizes, int n_in,
                              void* d_out, int out_size, void* d_ws, size_t ws_size,
                              hipStream_t stream) {
  const float* z     = (const float*)d_in[0];
  const float* in_w  = (const float*)d_in[1];
  const float* in_b  = (const float*)d_in[2];
  const float* out_w = (const float*)d_in[3];
  const float* out_b = (const float*)d_in[4];
  const float* cbk   = (const float*)d_in[5];
  float* out = (float*)d_out;
  float* ws  = (float*)d_ws;
  const float* ze = out + OFF_ZE;

  const size_t p8 = (size_t)NCH8*NB*DC*TT;   // 4,194,304 floats
  const size_t p4 = (size_t)NCH4*NB*DC*TT;   // 2,097,152 floats
  const size_t zqsz = (size_t)NB*DC*TT;      //   524,288
  const size_t cdsz = (size_t)KSP*NB*TT*2;   //   524,288
  const bool big = ws_size >= (p8 + zqsz + cdsz + 256)*sizeof(float);
  const size_t psz = big ? p8 : p4;

  float* P    = ws;
  float* ZQ   = P  + psz;
  float* CAND = ZQ + zqsz;
  float* LP   = CAND + cdsz;

  if (big) {
    vq_k1_ch8<<<dim3(8, NB, NCH8), 256, 0, stream>>>(z, in_w, P);
    vq_k2a<NCH8><<<dim3(NTT, NB), 256, 0, stream>>>(P, in_b, out);
  } else {
    vq_k1_ch4<<<dim3(NTT, NB, NCH4), 256, 0, stream>>>(z, in_w, P);
    vq_k2a<NCH4><<<dim3(NTT, NB), 256, 0, stream>>>(P, in_b, out);
  }
  vq_k2b<<<dim3(TT/T2TILE, NB, KSP), 256, 0, stream>>>(cbk, ze, CAND);
  vq_k2c<<<dim3(NTT, NB), 256, 0, stream>>>(CAND, ze, cbk, out, ZQ, LP);
  vq_k3_outproj<<<dim3(TT/1024, NB, NOC), 256, 0, stream>>>(ZQ, out_w, out_b, out);
  vq_k4_loss<<<1, 256, 0, stream>>>(LP, out);
}

// Round 7
// 175.122 us; speedup vs baseline: 6.2384x; 1.1796x over previous
//
#include <hip/hip_runtime.h>
#include <math.h>

#define NB   16
#define DIN  1024
#define TT   4096
#define DC   8
#define NK   1024
#define TILE 256
#define NTT  (TT/TILE)    // 16
#define DCH  256
#define NDC  (DIN/DCH)    // 4
#define OCH  128
#define NOC  (DIN/OCH)    // 8
// K2b: k-split x4, 4 t/thread
#define KSP    4
#define KCODES (NK/KSP)   // 256
#define T2TILE 1024       // 256 threads * 4 t

// d_out offsets (floats), in reference return order
#define OFF_CL  ((size_t)NB*DIN*TT)
#define OFF_CB  (OFF_CL + NB)
#define OFF_IDX (OFF_CB + NB)
#define OFF_ZE  (OFF_IDX + (size_t)NB*TT)

// ---------------- K1: in_proj partial sums (round-1, measured) ----------------
__global__ __launch_bounds__(256) void vq_k1_inproj(const float* __restrict__ z,
    const float* __restrict__ in_w, float* __restrict__ P)
{
  __shared__ float wt[DCH*DC];
  const int tid = threadIdx.x;
  const int tt = blockIdx.x, b = blockIdx.y, dc = blockIdx.z;
  const int dbase = dc*DCH;
  #pragma unroll
  for (int o = 0; o < DC; ++o)
    wt[tid*DC + o] = in_w[o*DIN + dbase + tid];
  __syncthreads();
  const int t = tt*TILE + tid;
  const float* zp = z + ((size_t)b*DIN + dbase)*TT + t;
  float acc[DC];
  #pragma unroll
  for (int o = 0; o < DC; ++o) acc[o] = 0.f;
  #pragma unroll 8
  for (int d = 0; d < DCH; ++d) {
    const float v = zp[(size_t)d*TT];
    const float4 w0 = *(const float4*)&wt[d*DC];
    const float4 w1 = *(const float4*)&wt[d*DC+4];
    acc[0] = fmaf(v, w0.x, acc[0]);
    acc[1] = fmaf(v, w0.y, acc[1]);
    acc[2] = fmaf(v, w0.z, acc[2]);
    acc[3] = fmaf(v, w0.w, acc[3]);
    acc[4] = fmaf(v, w1.x, acc[4]);
    acc[5] = fmaf(v, w1.y, acc[5]);
    acc[6] = fmaf(v, w1.z, acc[6]);
    acc[7] = fmaf(v, w1.w, acc[7]);
  }
  float* pp = P + ((size_t)(dc*NB + b)*DC)*TT + t;
  #pragma unroll
  for (int o = 0; o < DC; ++o) pp[(size_t)o*TT] = acc[o];
}

// ---------------- K2a: combine partials + bias -> z_e (round-1 combine chain) ----------------
__global__ __launch_bounds__(256) void vq_k2a(const float* __restrict__ P,
    const float* __restrict__ in_b, float* __restrict__ dout)
{
  const int tid = threadIdx.x;
  const int tt = blockIdx.x, b = blockIdx.y;
  const int t = tt*TILE + tid;
  const float* pp = P + ((size_t)b*DC)*TT + t;
  const size_t cs = (size_t)NB*DC*TT;
  #pragma unroll
  for (int o = 0; o < DC; ++o) {
    float s = pp[(size_t)o*TT];
    s += pp[cs   + (size_t)o*TT];
    s += pp[2*cs + (size_t)o*TT];
    s += pp[3*cs + (size_t)o*TT];
    dout[OFF_ZE + ((size_t)b*DC + o)*TT + t] = s + in_b[o];
  }
}

// ---------------- K2b: k-split codebook scan, 4 t/thread ----------------
__global__ __launch_bounds__(256) void vq_k2b(const float* __restrict__ cbk,
    const float* __restrict__ ze, float* __restrict__ cand)
{
  __shared__ float cns[KCODES*DC];   // 8 KB
  __shared__ float cn2s[KCODES];     // 1 KB
  const int tid = threadIdx.x;
  const int tb = blockIdx.x, b = blockIdx.y, kp = blockIdx.z;
  const int k0 = kp*KCODES;

  // stage + normalize this partition (round-1 chain)
  {
    const int k = k0 + tid;
    float c[DC];
    const float4 c0 = *(const float4*)&cbk[k*DC];
    const float4 c1 = *(const float4*)&cbk[k*DC+4];
    c[0]=c0.x; c[1]=c0.y; c[2]=c0.z; c[3]=c0.w;
    c[4]=c1.x; c[5]=c1.y; c[6]=c1.z; c[7]=c1.w;
    float ss = 0.f;
    #pragma unroll
    for (int i = 0; i < DC; ++i) ss = fmaf(c[i], c[i], ss);
    const float den = fmaxf(sqrtf(ss), 1e-12f);
    float s2 = 0.f;
    #pragma unroll
    for (int i = 0; i < DC; ++i) { const float v = c[i]/den; cns[tid*DC+i] = v; s2 = fmaf(v, v, s2); }
    cn2s[tid] = s2;
  }
  __syncthreads();

  const int t0 = tb*T2TILE + tid*4;
  // load e for 4 t's (float4 over t per channel), normalize each (round-1 chain)
  float en[4][DC], en2[4];
  #pragma unroll
  for (int o = 0; o < DC; ++o) {
    const float4 v = *(const float4*)&ze[((size_t)b*DC + o)*TT + t0];
    en[0][o]=v.x; en[1][o]=v.y; en[2][o]=v.z; en[3][o]=v.w;
  }
  #pragma unroll
  for (int j = 0; j < 4; ++j) {
    float se = 0.f;
    #pragma unroll
    for (int i = 0; i < DC; ++i) se = fmaf(en[j][i], en[j][i], se);
    const float dene = fmaxf(sqrtf(se), 1e-12f);
    float s2 = 0.f;
    #pragma unroll
    for (int i = 0; i < DC; ++i) { en[j][i] /= dene; s2 = fmaf(en[j][i], en[j][i], s2); }
    en2[j] = s2;
  }

  float bd[4]; int bk[4];
  #pragma unroll
  for (int j = 0; j < 4; ++j) { bd[j] = 3.4e38f; bk[j] = k0; }
  #pragma unroll 2
  for (int k = 0; k < KCODES; ++k) {
    const float4 a0 = *(const float4*)&cns[k*DC];
    const float4 a1 = *(const float4*)&cns[k*DC+4];
    const float c2 = cn2s[k];
    #pragma unroll
    for (int j = 0; j < 4; ++j) {
      float dacc = en[j][0]*a0.x;
      dacc = fmaf(en[j][1], a0.y, dacc);
      dacc = fmaf(en[j][2], a0.z, dacc);
      dacc = fmaf(en[j][3], a0.w, dacc);
      dacc = fmaf(en[j][4], a1.x, dacc);
      dacc = fmaf(en[j][5], a1.y, dacc);
      dacc = fmaf(en[j][6], a1.z, dacc);
      dacc = fmaf(en[j][7], a1.w, dacc);
      const float dist = (en2[j] - 2.0f*dacc) + c2;   // round-1 exact chain
      if (dist < bd[j]) { bd[j] = dist; bk[j] = k0 + k; }
    }
  }
  float* cp = cand + ((size_t)(kp*NB + b)*TT + t0)*2;
  *(float4*)&cp[0] = make_float4(bd[0], __int_as_float(bk[0]), bd[1], __int_as_float(bk[1]));
  *(float4*)&cp[4] = make_float4(bd[2], __int_as_float(bk[2]), bd[3], __int_as_float(bk[3]));
}

// ---------------- K2c: merge partitions + rotation trick + loss ----------------
__global__ __launch_bounds__(256) void vq_k2c(const float* __restrict__ cand,
    const float* __restrict__ ze, const float* __restrict__ cbk,
    float* __restrict__ dout, float* __restrict__ zq, float* __restrict__ lpart)
{
  __shared__ float lred[256];
  const int tid = threadIdx.x;
  const int tt = blockIdx.x, b = blockIdx.y;
  const int t = tt*TILE + tid;

  // merge in ascending-partition order, strict < => global first occurrence
  float bd; int bk;
  {
    const float2 c0 = *(const float2*)&cand[((size_t)(0*NB + b)*TT + t)*2];
    bd = c0.x; bk = __float_as_int(c0.y);
    #pragma unroll
    for (int kp = 1; kp < KSP; ++kp) {
      const float2 c = *(const float2*)&cand[((size_t)(kp*NB + b)*TT + t)*2];
      if (c.x < bd) { bd = c.x; bk = __float_as_int(c.y); }
    }
  }
  dout[OFF_IDX + (size_t)b*TT + t] = (float)bk;

  float e[DC], en[DC];
  #pragma unroll
  for (int o = 0; o < DC; ++o) e[o] = ze[((size_t)b*DC + o)*TT + t];
  float se = 0.f;
  #pragma unroll
  for (int i = 0; i < DC; ++i) se = fmaf(e[i], e[i], se);
  const float ne = sqrtf(se);
  const float dene = fmaxf(ne, 1e-12f);
  #pragma unroll
  for (int i = 0; i < DC; ++i) en[i] = e[i]/dene;

  float q[DC];
  {
    const float4 q0 = *(const float4*)&cbk[bk*DC];
    const float4 q1 = *(const float4*)&cbk[bk*DC+4];
    q[0]=q0.x; q[1]=q0.y; q[2]=q0.z; q[3]=q0.w;
    q[4]=q1.x; q[5]=q1.y; q[6]=q1.z; q[7]=q1.w;
  }
  float cl = 0.f;
  #pragma unroll
  for (int i = 0; i < DC; ++i) { const float d = e[i]-q[i]; cl = fmaf(d, d, cl); }

  float sq = 0.f;
  #pragma unroll
  for (int i = 0; i < DC; ++i) sq = fmaf(q[i], q[i], sq);
  const float nq = sqrtf(sq);
  const float denq = fmaxf(nq, 1e-12f);
  float qn[DC], rr[DC];
  float sr = 0.f;
  #pragma unroll
  for (int i = 0; i < DC; ++i) { qn[i] = q[i]/denq; rr[i] = en[i]+qn[i]; sr = fmaf(rr[i], rr[i], sr); }
  const float denr = fmaxf(sqrtf(sr), 1e-12f);
  float r_[DC];
  float rdz = 0.f, edz = 0.f;
  #pragma unroll
  for (int i = 0; i < DC; ++i) { r_[i] = rr[i]/denr; rdz = fmaf(r_[i], e[i], rdz); edz = fmaf(en[i], e[i], edz); }
  const float scal = nq / fmaxf(ne, 1e-8f);
  #pragma unroll
  for (int i = 0; i < DC; ++i) {
    const float v = scal * ((e[i] - 2.0f*r_[i]*rdz) + 2.0f*qn[i]*edz);
    zq[((size_t)b*DC + i)*TT + t] = v;
  }

  lred[tid] = cl;
  __syncthreads();
  for (int s = 128; s > 0; s >>= 1) {
    if (tid < s) lred[tid] += lred[tid + s];
    __syncthreads();
  }
  if (tid == 0) lpart[b*NTT + tt] = lred[0];
}

// ---------------- K3: out_proj (round-1, measured) ----------------
__global__ __launch_bounds__(256) void vq_k3_outproj(const float* __restrict__ zq,
    const float* __restrict__ out_w, const float* __restrict__ out_b,
    float* __restrict__ dout)
{
  __shared__ float wo[OCH*DC];
  __shared__ float ob[OCH];
  const int tid = threadIdx.x;
  const int tt = blockIdx.x, b = blockIdx.y, oc = blockIdx.z;
  const int obase = oc*OCH;
  for (int i = tid; i < OCH*DC; i += 256) wo[i] = out_w[obase*DC + i];
  if (tid < OCH) ob[tid] = out_b[obase + tid];
  __syncthreads();
  const int t = tt*TILE + tid;
  float zr[DC];
  #pragma unroll
  for (int c = 0; c < DC; ++c) zr[c] = zq[((size_t)b*DC + c)*TT + t];
  float* op = dout + ((size_t)b*DIN + obase)*TT + t;
  #pragma unroll 4
  for (int o = 0; o < OCH; ++o) {
    const float4 w0 = *(const float4*)&wo[o*DC];
    const float4 w1 = *(const float4*)&wo[o*DC+4];
    float s = ob[o];
    s = fmaf(zr[0], w0.x, s);
    s = fmaf(zr[1], w0.y, s);
    s = fmaf(zr[2], w0.z, s);
    s = fmaf(zr[3], w0.w, s);
    s = fmaf(zr[4], w1.x, s);
    s = fmaf(zr[5], w1.y, s);
    s = fmaf(zr[6], w1.z, s);
    s = fmaf(zr[7], w1.w, s);
    op[(size_t)o*TT] = s;
  }
}

// ---------------- K4: loss finalize ----------------
__global__ void vq_k4_loss(const float* __restrict__ lpart, float* __restrict__ dout)
{
  const int b = threadIdx.x;
  if (b < NB) {
    float s = 0.f;
    for (int j = 0; j < NTT; ++j) s += lpart[b*NTT + j];
    const float v = s / (float)(TT*DC);
    dout[OFF_CL + b] = v;
    dout[OFF_CB + b] = v;
  }
}

extern "C" void kernel_launch(void* const* d_in, const int* in_sizes, int n_in,
                              void* d_out, int out_size, void* d_ws, size_t ws_size,
                              hipStream_t stream) {
  const float* z     = (const float*)d_in[0];
  const float* in_w  = (const float*)d_in[1];
  const float* in_b  = (const float*)d_in[2];
  const float* out_w = (const float*)d_in[3];
  const float* out_b = (const float*)d_in[4];
  const float* cbk   = (const float*)d_in[5];
  float* out = (float*)d_out;
  float* ws  = (float*)d_ws;
  const float* ze = out + OFF_ZE;

  float* P    = ws;                              // 2,097,152 floats
  float* ZQ   = P  + (size_t)NDC*NB*DC*TT;       //   524,288 floats
  float* CAND = ZQ + (size_t)NB*DC*TT;           //   524,288 floats
  float* LP   = CAND + (size_t)KSP*NB*TT*2;      //       256 floats

  vq_k1_inproj <<<dim3(NTT, NB, NDC), 256, 0, stream>>>(z, in_w, P);
  vq_k2a       <<<dim3(NTT, NB),      256, 0, stream>>>(P, in_b, out);
  vq_k2b       <<<dim3(TT/T2TILE, NB, KSP), 256, 0, stream>>>(cbk, ze, CAND);
  vq_k2c       <<<dim3(NTT, NB),      256, 0, stream>>>(CAND, ze, cbk, out, ZQ, LP);
  vq_k3_outproj<<<dim3(NTT, NB, NOC), 256, 0, stream>>>(ZQ, out_w, out_b, out);
  vq_k4_loss   <<<1, 256, 0, stream>>>(LP, out);
}

// Round 8
// 175.022 us; speedup vs baseline: 6.2419x; 1.0006x over previous
//
#include <hip/hip_runtime.h>
#include <math.h>

#define NB   16
#define DIN  1024
#define TT   4096
#define DC   8
#define NK   1024
#define TILE 256
#define NTT  (TT/TILE)    // 16
#define DCH  256
#define NDC  (DIN/DCH)    // 4
#define OCH  128
#define NOC  (DIN/OCH)    // 8
// K1/K3: 2 t/thread, t-tile 512
#define T1TILE 512
// K2b: k-split x8, 8 t/thread
#define KSP    8
#define KCODES (NK/KSP)   // 128
#define T2TILE 2048       // 256 threads * 8 t

// d_out offsets (floats), in reference return order
#define OFF_CL  ((size_t)NB*DIN*TT)
#define OFF_CB  (OFF_CL + NB)
#define OFF_IDX (OFF_CB + NB)
#define OFF_ZE  (OFF_IDX + (size_t)NB*TT)

// ---------------- K1: in_proj partials, float2 (2 t/thread), d-split x4 ----------------
__global__ __launch_bounds__(256) void vq_k1_inproj(const float* __restrict__ z,
    const float* __restrict__ in_w, float* __restrict__ P)
{
  __shared__ float wt[DCH*DC];
  const int tid = threadIdx.x;
  const int tt = blockIdx.x, b = blockIdx.y, dc = blockIdx.z;
  const int dbase = dc*DCH;
  #pragma unroll
  for (int o = 0; o < DC; ++o)
    wt[tid*DC + o] = in_w[o*DIN + dbase + tid];
  __syncthreads();
  const int t = tt*T1TILE + tid*2;
  const float* zp = z + ((size_t)b*DIN + dbase)*TT + t;
  float ax[DC], ay[DC];
  #pragma unroll
  for (int o = 0; o < DC; ++o) { ax[o] = 0.f; ay[o] = 0.f; }
  #pragma unroll 8
  for (int d = 0; d < DCH; ++d) {
    const float2 v = *(const float2*)&zp[(size_t)d*TT];
    const float4 w0 = *(const float4*)&wt[d*DC];
    const float4 w1 = *(const float4*)&wt[d*DC+4];
    ax[0] = fmaf(v.x, w0.x, ax[0]);  ay[0] = fmaf(v.y, w0.x, ay[0]);
    ax[1] = fmaf(v.x, w0.y, ax[1]);  ay[1] = fmaf(v.y, w0.y, ay[1]);
    ax[2] = fmaf(v.x, w0.z, ax[2]);  ay[2] = fmaf(v.y, w0.z, ay[2]);
    ax[3] = fmaf(v.x, w0.w, ax[3]);  ay[3] = fmaf(v.y, w0.w, ay[3]);
    ax[4] = fmaf(v.x, w1.x, ax[4]);  ay[4] = fmaf(v.y, w1.x, ay[4]);
    ax[5] = fmaf(v.x, w1.y, ax[5]);  ay[5] = fmaf(v.y, w1.y, ay[5]);
    ax[6] = fmaf(v.x, w1.z, ax[6]);  ay[6] = fmaf(v.y, w1.z, ay[6]);
    ax[7] = fmaf(v.x, w1.w, ax[7]);  ay[7] = fmaf(v.y, w1.w, ay[7]);
  }
  float* pp = P + ((size_t)(dc*NB + b)*DC)*TT + t;
  #pragma unroll
  for (int o = 0; o < DC; ++o)
    *(float2*)&pp[(size_t)o*TT] = make_float2(ax[o], ay[o]);
}

// ---------------- K2a: combine partials + bias -> z_e (round-7, unchanged) ----------------
__global__ __launch_bounds__(256) void vq_k2a(const float* __restrict__ P,
    const float* __restrict__ in_b, float* __restrict__ dout)
{
  const int tid = threadIdx.x;
  const int tt = blockIdx.x, b = blockIdx.y;
  const int t = tt*TILE + tid;
  const float* pp = P + ((size_t)b*DC)*TT + t;
  const size_t cs = (size_t)NB*DC*TT;
  #pragma unroll
  for (int o = 0; o < DC; ++o) {
    float s = pp[(size_t)o*TT];
    s += pp[cs   + (size_t)o*TT];
    s += pp[2*cs + (size_t)o*TT];
    s += pp[3*cs + (size_t)o*TT];
    dout[OFF_ZE + ((size_t)b*DC + o)*TT + t] = s + in_b[o];
  }
}

// ---------------- K2b: k-split x8 codebook scan, 8 t/thread ----------------
__global__ __launch_bounds__(256) void vq_k2b(const float* __restrict__ cbk,
    const float* __restrict__ ze, float* __restrict__ cand)
{
  __shared__ float cns[KCODES*DC];   // 4 KB
  __shared__ float cn2s[KCODES];     // 512 B
  const int tid = threadIdx.x;
  const int tb = blockIdx.x, b = blockIdx.y, kp = blockIdx.z;
  const int k0 = kp*KCODES;

  if (tid < KCODES) {
    const int k = k0 + tid;
    float c[DC];
    const float4 c0 = *(const float4*)&cbk[k*DC];
    const float4 c1 = *(const float4*)&cbk[k*DC+4];
    c[0]=c0.x; c[1]=c0.y; c[2]=c0.z; c[3]=c0.w;
    c[4]=c1.x; c[5]=c1.y; c[6]=c1.z; c[7]=c1.w;
    float ss = 0.f;
    #pragma unroll
    for (int i = 0; i < DC; ++i) ss = fmaf(c[i], c[i], ss);
    const float den = fmaxf(sqrtf(ss), 1e-12f);
    float s2 = 0.f;
    #pragma unroll
    for (int i = 0; i < DC; ++i) { const float v = c[i]/den; cns[tid*DC+i] = v; s2 = fmaf(v, v, s2); }
    cn2s[tid] = s2;
  }
  __syncthreads();

  const int t0 = tb*T2TILE + tid*8;
  float en[8][DC], en2[8];
  #pragma unroll
  for (int o = 0; o < DC; ++o) {
    const float4 va = *(const float4*)&ze[((size_t)b*DC + o)*TT + t0];
    const float4 vb = *(const float4*)&ze[((size_t)b*DC + o)*TT + t0 + 4];
    en[0][o]=va.x; en[1][o]=va.y; en[2][o]=va.z; en[3][o]=va.w;
    en[4][o]=vb.x; en[5][o]=vb.y; en[6][o]=vb.z; en[7][o]=vb.w;
  }
  #pragma unroll
  for (int j = 0; j < 8; ++j) {
    float se = 0.f;
    #pragma unroll
    for (int i = 0; i < DC; ++i) se = fmaf(en[j][i], en[j][i], se);
    const float dene = fmaxf(sqrtf(se), 1e-12f);
    float s2 = 0.f;
    #pragma unroll
    for (int i = 0; i < DC; ++i) { en[j][i] /= dene; s2 = fmaf(en[j][i], en[j][i], s2); }
    en2[j] = s2;
  }

  float bd[8]; int bk[8];
  #pragma unroll
  for (int j = 0; j < 8; ++j) { bd[j] = 3.4e38f; bk[j] = k0; }
  for (int k = 0; k < KCODES; ++k) {
    const float4 a0 = *(const float4*)&cns[k*DC];
    const float4 a1 = *(const float4*)&cns[k*DC+4];
    const float c2 = cn2s[k];
    #pragma unroll
    for (int j = 0; j < 8; ++j) {
      float dacc = en[j][0]*a0.x;
      dacc = fmaf(en[j][1], a0.y, dacc);
      dacc = fmaf(en[j][2], a0.z, dacc);
      dacc = fmaf(en[j][3], a0.w, dacc);
      dacc = fmaf(en[j][4], a1.x, dacc);
      dacc = fmaf(en[j][5], a1.y, dacc);
      dacc = fmaf(en[j][6], a1.z, dacc);
      dacc = fmaf(en[j][7], a1.w, dacc);
      const float dist = (en2[j] - 2.0f*dacc) + c2;   // round-1 exact chain
      if (dist < bd[j]) { bd[j] = dist; bk[j] = k0 + k; }
    }
  }
  float* cp = cand + ((size_t)(kp*NB + b)*TT + t0)*2;
  #pragma unroll
  for (int j = 0; j < 4; ++j)
    *(float4*)&cp[j*4] = make_float4(bd[2*j], __int_as_float(bk[2*j]),
                                     bd[2*j+1], __int_as_float(bk[2*j+1]));
}

// ---------------- K2c: merge partitions + rotation trick + loss ----------------
__global__ __launch_bounds__(256) void vq_k2c(const float* __restrict__ cand,
    const float* __restrict__ ze, const float* __restrict__ cbk,
    float* __restrict__ dout, float* __restrict__ zq, float* __restrict__ lpart)
{
  __shared__ float lred[256];
  const int tid = threadIdx.x;
  const int tt = blockIdx.x, b = blockIdx.y;
  const int t = tt*TILE + tid;

  // merge in ascending-partition order, strict < => global first occurrence
  float bd; int bk;
  {
    const float2 c0 = *(const float2*)&cand[((size_t)(0*NB + b)*TT + t)*2];
    bd = c0.x; bk = __float_as_int(c0.y);
    #pragma unroll
    for (int kp = 1; kp < KSP; ++kp) {
      const float2 c = *(const float2*)&cand[((size_t)(kp*NB + b)*TT + t)*2];
      if (c.x < bd) { bd = c.x; bk = __float_as_int(c.y); }
    }
  }
  dout[OFF_IDX + (size_t)b*TT + t] = (float)bk;

  float e[DC], en[DC];
  #pragma unroll
  for (int o = 0; o < DC; ++o) e[o] = ze[((size_t)b*DC + o)*TT + t];
  float se = 0.f;
  #pragma unroll
  for (int i = 0; i < DC; ++i) se = fmaf(e[i], e[i], se);
  const float ne = sqrtf(se);
  const float dene = fmaxf(ne, 1e-12f);
  #pragma unroll
  for (int i = 0; i < DC; ++i) en[i] = e[i]/dene;

  float q[DC];
  {
    const float4 q0 = *(const float4*)&cbk[bk*DC];
    const float4 q1 = *(const float4*)&cbk[bk*DC+4];
    q[0]=q0.x; q[1]=q0.y; q[2]=q0.z; q[3]=q0.w;
    q[4]=q1.x; q[5]=q1.y; q[6]=q1.z; q[7]=q1.w;
  }
  float cl = 0.f;
  #pragma unroll
  for (int i = 0; i < DC; ++i) { const float d = e[i]-q[i]; cl = fmaf(d, d, cl); }

  float sq = 0.f;
  #pragma unroll
  for (int i = 0; i < DC; ++i) sq = fmaf(q[i], q[i], sq);
  const float nq = sqrtf(sq);
  const float denq = fmaxf(nq, 1e-12f);
  float qn[DC], rr[DC];
  float sr = 0.f;
  #pragma unroll
  for (int i = 0; i < DC; ++i) { qn[i] = q[i]/denq; rr[i] = en[i]+qn[i]; sr = fmaf(rr[i], rr[i], sr); }
  const float denr = fmaxf(sqrtf(sr), 1e-12f);
  float r_[DC];
  float rdz = 0.f, edz = 0.f;
  #pragma unroll
  for (int i = 0; i < DC; ++i) { r_[i] = rr[i]/denr; rdz = fmaf(r_[i], e[i], rdz); edz = fmaf(en[i], e[i], edz); }
  const float scal = nq / fmaxf(ne, 1e-8f);
  #pragma unroll
  for (int i = 0; i < DC; ++i) {
    const float v = scal * ((e[i] - 2.0f*r_[i]*rdz) + 2.0f*qn[i]*edz);
    zq[((size_t)b*DC + i)*TT + t] = v;
  }

  lred[tid] = cl;
  __syncthreads();
  for (int s = 128; s > 0; s >>= 1) {
    if (tid < s) lred[tid] += lred[tid + s];
    __syncthreads();
  }
  if (tid == 0) lpart[b*NTT + tt] = lred[0];
}

// ---------------- K3: out_proj, float2 (2 t/thread), o-chunk 128 ----------------
__global__ __launch_bounds__(256) void vq_k3_outproj(const float* __restrict__ zq,
    const float* __restrict__ out_w, const float* __restrict__ out_b,
    float* __restrict__ dout)
{
  __shared__ float wo[OCH*DC];
  __shared__ float ob[OCH];
  const int tid = threadIdx.x;
  const int tb = blockIdx.x, b = blockIdx.y, oc = blockIdx.z;
  const int obase = oc*OCH;
  for (int i = tid; i < OCH*DC; i += 256) wo[i] = out_w[obase*DC + i];
  if (tid < OCH) ob[tid] = out_b[obase + tid];
  __syncthreads();
  const int t = tb*T1TILE + tid*2;
  float zx[DC], zy[DC];
  #pragma unroll
  for (int c = 0; c < DC; ++c) {
    const float2 v = *(const float2*)&zq[((size_t)b*DC + c)*TT + t];
    zx[c] = v.x; zy[c] = v.y;
  }
  float* op = dout + ((size_t)b*DIN + obase)*TT + t;
  #pragma unroll 4
  for (int o = 0; o < OCH; ++o) {
    const float4 w0 = *(const float4*)&wo[o*DC];
    const float4 w1 = *(const float4*)&wo[o*DC+4];
    const float bv = ob[o];
    float s0 = bv, s1 = bv;
    s0 = fmaf(zx[0], w0.x, s0);  s1 = fmaf(zy[0], w0.x, s1);
    s0 = fmaf(zx[1], w0.y, s0);  s1 = fmaf(zy[1], w0.y, s1);
    s0 = fmaf(zx[2], w0.z, s0);  s1 = fmaf(zy[2], w0.z, s1);
    s0 = fmaf(zx[3], w0.w, s0);  s1 = fmaf(zy[3], w0.w, s1);
    s0 = fmaf(zx[4], w1.x, s0);  s1 = fmaf(zy[4], w1.x, s1);
    s0 = fmaf(zx[5], w1.y, s0);  s1 = fmaf(zy[5], w1.y, s1);
    s0 = fmaf(zx[6], w1.z, s0);  s1 = fmaf(zy[6], w1.z, s1);
    s0 = fmaf(zx[7], w1.w, s0);  s1 = fmaf(zy[7], w1.w, s1);
    *(float2*)&op[(size_t)o*TT] = make_float2(s0, s1);
  }
}

// ---------------- K4: loss finalize ----------------
__global__ void vq_k4_loss(const float* __restrict__ lpart, float* __restrict__ dout)
{
  const int b = threadIdx.x;
  if (b < NB) {
    float s = 0.f;
    for (int j = 0; j < NTT; ++j) s += lpart[b*NTT + j];
    const float v = s / (float)(TT*DC);
    dout[OFF_CL + b] = v;
    dout[OFF_CB + b] = v;
  }
}

extern "C" void kernel_launch(void* const* d_in, const int* in_sizes, int n_in,
                              void* d_out, int out_size, void* d_ws, size_t ws_size,
                              hipStream_t stream) {
  const float* z     = (const float*)d_in[0];
  const float* in_w  = (const float*)d_in[1];
  const float* in_b  = (const float*)d_in[2];
  const float* out_w = (const float*)d_in[3];
  const float* out_b = (const float*)d_in[4];
  const float* cbk   = (const float*)d_in[5];
  float* out = (float*)d_out;
  float* ws  = (float*)d_ws;
  const float* ze = out + OFF_ZE;

  float* P    = ws;                              // 2,097,152 floats
  float* ZQ   = P  + (size_t)NDC*NB*DC*TT;       //   524,288 floats
  float* CAND = ZQ + (size_t)NB*DC*TT;           // 1,048,576 floats
  float* LP   = CAND + (size_t)KSP*NB*TT*2;      //       256 floats

  vq_k1_inproj <<<dim3(TT/T1TILE, NB, NDC), 256, 0, stream>>>(z, in_w, P);
  vq_k2a       <<<dim3(NTT, NB),            256, 0, stream>>>(P, in_b, out);
  vq_k2b       <<<dim3(TT/T2TILE, NB, KSP), 256, 0, stream>>>(cbk, ze, CAND);
  vq_k2c       <<<dim3(NTT, NB),            256, 0, stream>>>(CAND, ze, cbk, out, ZQ, LP);
  vq_k3_outproj<<<dim3(TT/T1TILE, NB, NOC), 256, 0, stream>>>(ZQ, out_w, out_b, out);
  vq_k4_loss   <<<1, 256, 0, stream>>>(LP, out);
}

// Round 9
// 160.942 us; speedup vs baseline: 6.7880x; 1.0875x over previous
//
#include <hip/hip_runtime.h>
#include <math.h>

#define NB   16
#define DIN  1024
#define TT   4096
#define DC   8
#define NK   1024
// KA: 512 threads, t-tile 128, in-block d-split x4
#define TA   128
#define NTA  (TT/TA)      // 32
// KB: 512 threads, t-tile 128, in-block k-split x16 (64 codes), 4 t/thread
#define NPG  16
#define KCP  (NK/NPG)     // 64
// KC: o-chunk 128, float2 (2 t/thread), t-tile 512  (round-8 K3, proven)
#define OCH  128
#define NOC  (DIN/OCH)    // 8
#define T3TILE 512

// d_out offsets (floats), in reference return order
#define OFF_CL  ((size_t)NB*DIN*TT)
#define OFF_CB  (OFF_CL + NB)
#define OFF_IDX (OFF_CB + NB)
#define OFF_ZE  (OFF_IDX + (size_t)NB*TT)

// ---------------- KA: in_proj (in-block d-split) + bias -> z_e ----------------
__global__ __launch_bounds__(512) void vq_kA(const float* __restrict__ z,
    const float* __restrict__ in_w, const float* __restrict__ in_b,
    float* __restrict__ dout)
{
  __shared__ float wt[DIN*DC];        // 32 KB, [d][o]
  __shared__ float pacc[4][TA][DC];   // 16 KB
  const int tid = threadIdx.x;
  const int tb = blockIdx.x, b = blockIdx.y;
  for (int i = tid; i < DIN*DC; i += 512) {
    const int d = i >> 3, o = i & 7;
    wt[i] = in_w[o*DIN + d];
  }
  __syncthreads();
  const int sub = tid >> 7, tl = tid & 127;
  const int t = tb*TA + tl;
  const int dbase = sub*256;
  const float* zp = z + ((size_t)b*DIN + dbase)*TT + t;
  float acc[DC];
  #pragma unroll
  for (int o = 0; o < DC; ++o) acc[o] = 0.f;
  #pragma unroll 8
  for (int d = 0; d < 256; ++d) {
    const float v = zp[(size_t)d*TT];
    const float4 w0 = *(const float4*)&wt[(dbase+d)*DC];
    const float4 w1 = *(const float4*)&wt[(dbase+d)*DC+4];
    acc[0] = fmaf(v, w0.x, acc[0]);
    acc[1] = fmaf(v, w0.y, acc[1]);
    acc[2] = fmaf(v, w0.z, acc[2]);
    acc[3] = fmaf(v, w0.w, acc[3]);
    acc[4] = fmaf(v, w1.x, acc[4]);
    acc[5] = fmaf(v, w1.y, acc[5]);
    acc[6] = fmaf(v, w1.z, acc[6]);
    acc[7] = fmaf(v, w1.w, acc[7]);
  }
  *(float4*)&pacc[sub][tl][0] = make_float4(acc[0], acc[1], acc[2], acc[3]);
  *(float4*)&pacc[sub][tl][4] = make_float4(acc[4], acc[5], acc[6], acc[7]);
  __syncthreads();
  // combine ascending chunk order (== round-1 chain), 2 (o,t) pairs per thread
  #pragma unroll
  for (int oo = 0; oo < 2; ++oo) {
    const int o = (tid >> 7) + oo*4;
    float s = pacc[0][tl][o];
    s += pacc[1][tl][o];
    s += pacc[2][tl][o];
    s += pacc[3][tl][o];
    dout[OFF_ZE + ((size_t)b*DC + o)*TT + t] = s + in_b[o];
  }
}

// ---------------- KB: VQ scan (in-block k-split x16, 4 t/thread) + merge + rotation + loss ----------------
__global__ __launch_bounds__(512) void vq_kB(const float* __restrict__ ze,
    const float* __restrict__ cbk, float* __restrict__ dout,
    float* __restrict__ zq, float* __restrict__ lpart)
{
  __shared__ float cn[NK*DC];         // 32 KB
  __shared__ float cn2[NK];           // 4 KB
  __shared__ float2 cand[NPG][TA];    // 16 KB
  __shared__ float lred[TA];          // 512 B
  const int tid = threadIdx.x;
  const int tb = blockIdx.x, b = blockIdx.y;

  // stage + normalize codebook (exact round-1 chain)
  for (int k = tid; k < NK; k += 512) {
    float c[DC];
    const float4 c0 = *(const float4*)&cbk[k*DC];
    const float4 c1 = *(const float4*)&cbk[k*DC+4];
    c[0]=c0.x; c[1]=c0.y; c[2]=c0.z; c[3]=c0.w;
    c[4]=c1.x; c[5]=c1.y; c[6]=c1.z; c[7]=c1.w;
    float ss = 0.f;
    #pragma unroll
    for (int i = 0; i < DC; ++i) ss = fmaf(c[i], c[i], ss);
    const float den = fmaxf(sqrtf(ss), 1e-12f);
    float s2 = 0.f;
    #pragma unroll
    for (int i = 0; i < DC; ++i) { const float v = c[i]/den; cn[k*DC+i] = v; s2 = fmaf(v, v, s2); }
    cn2[k] = s2;
  }
  __syncthreads();

  const int pg = tid >> 5, l = tid & 31;
  const int k0 = pg*KCP;
  // 4 t per thread: t = tb*TA + l + 32*m
  float en[4][DC], en2[4];
  #pragma unroll
  for (int m = 0; m < 4; ++m) {
    const int t = tb*TA + l + 32*m;
    float e[DC];
    #pragma unroll
    for (int o = 0; o < DC; ++o) e[o] = ze[((size_t)b*DC + o)*TT + t];
    float se = 0.f;
    #pragma unroll
    for (int i = 0; i < DC; ++i) se = fmaf(e[i], e[i], se);
    const float dene = fmaxf(sqrtf(se), 1e-12f);
    float s2 = 0.f;
    #pragma unroll
    for (int i = 0; i < DC; ++i) { en[m][i] = e[i]/dene; s2 = fmaf(en[m][i], en[m][i], s2); }
    en2[m] = s2;
  }
  float bd[4]; int bk[4];
  #pragma unroll
  for (int m = 0; m < 4; ++m) { bd[m] = 3.4e38f; bk[m] = k0; }
  #pragma unroll 2
  for (int k = 0; k < KCP; ++k) {
    const float4 a0 = *(const float4*)&cn[(k0+k)*DC];
    const float4 a1 = *(const float4*)&cn[(k0+k)*DC+4];
    const float c2 = cn2[k0+k];
    #pragma unroll
    for (int m = 0; m < 4; ++m) {
      float dacc = en[m][0]*a0.x;
      dacc = fmaf(en[m][1], a0.y, dacc);
      dacc = fmaf(en[m][2], a0.z, dacc);
      dacc = fmaf(en[m][3], a0.w, dacc);
      dacc = fmaf(en[m][4], a1.x, dacc);
      dacc = fmaf(en[m][5], a1.y, dacc);
      dacc = fmaf(en[m][6], a1.z, dacc);
      dacc = fmaf(en[m][7], a1.w, dacc);
      const float dist = (en2[m] - 2.0f*dacc) + c2;   // exact round-1 chain
      if (dist < bd[m]) { bd[m] = dist; bk[m] = k0 + k; }
    }
  }
  #pragma unroll
  for (int m = 0; m < 4; ++m)
    cand[pg][l + 32*m] = make_float2(bd[m], __float_as_int(bk[m]) ? __int_as_float(bk[m]) : __int_as_float(bk[m]));
  __syncthreads();

  // merge (ascending pg => first occurrence) + rotation + loss: threads 0..127
  if (tid < TA) {
    const int tl = tid, t = tb*TA + tl;
    float bdm = cand[0][tl].x;
    int bkm = __float_as_int(cand[0][tl].y);
    #pragma unroll
    for (int p = 1; p < NPG; ++p) {
      const float2 c = cand[p][tl];
      if (c.x < bdm) { bdm = c.x; bkm = __float_as_int(c.y); }
    }
    dout[OFF_IDX + (size_t)b*TT + t] = (float)bkm;

    float e[DC], en_[DC];
    #pragma unroll
    for (int o = 0; o < DC; ++o) e[o] = ze[((size_t)b*DC + o)*TT + t];
    float se = 0.f;
    #pragma unroll
    for (int i = 0; i < DC; ++i) se = fmaf(e[i], e[i], se);
    const float ne = sqrtf(se);
    const float dene = fmaxf(ne, 1e-12f);
    #pragma unroll
    for (int i = 0; i < DC; ++i) en_[i] = e[i]/dene;

    float q[DC];
    {
      const float4 q0 = *(const float4*)&cbk[bkm*DC];
      const float4 q1 = *(const float4*)&cbk[bkm*DC+4];
      q[0]=q0.x; q[1]=q0.y; q[2]=q0.z; q[3]=q0.w;
      q[4]=q1.x; q[5]=q1.y; q[6]=q1.z; q[7]=q1.w;
    }
    float cl = 0.f;
    #pragma unroll
    for (int i = 0; i < DC; ++i) { const float d = e[i]-q[i]; cl = fmaf(d, d, cl); }

    float sq = 0.f;
    #pragma unroll
    for (int i = 0; i < DC; ++i) sq = fmaf(q[i], q[i], sq);
    const float nq = sqrtf(sq);
    const float denq = fmaxf(nq, 1e-12f);
    float qn[DC], rr[DC];
    float sr = 0.f;
    #pragma unroll
    for (int i = 0; i < DC; ++i) { qn[i] = q[i]/denq; rr[i] = en_[i]+qn[i]; sr = fmaf(rr[i], rr[i], sr); }
    const float denr = fmaxf(sqrtf(sr), 1e-12f);
    float r_[DC];
    float rdz = 0.f, edz = 0.f;
    #pragma unroll
    for (int i = 0; i < DC; ++i) { r_[i] = rr[i]/denr; rdz = fmaf(r_[i], e[i], rdz); edz = fmaf(en_[i], e[i], edz); }
    const float scal = nq / fmaxf(ne, 1e-8f);
    #pragma unroll
    for (int i = 0; i < DC; ++i) {
      const float v = scal * ((e[i] - 2.0f*r_[i]*rdz) + 2.0f*qn[i]*edz);
      zq[((size_t)b*DC + i)*TT + t] = v;
    }
    lred[tl] = cl;
  }
  __syncthreads();
  for (int s = TA/2; s > 0; s >>= 1) {
    if (tid < s) lred[tid] += lred[tid + s];
    __syncthreads();
  }
  if (tid == 0) lpart[b*NTA + tb] = lred[0];
}

// ---------------- KC: out_proj (round-8 K3, proven) + loss finalize tail ----------------
__global__ __launch_bounds__(256) void vq_kC(const float* __restrict__ zq,
    const float* __restrict__ out_w, const float* __restrict__ out_b,
    const float* __restrict__ lpart, float* __restrict__ dout)
{
  __shared__ float wo[OCH*DC];
  __shared__ float ob[OCH];
  const int tid = threadIdx.x;
  const int tb = blockIdx.x, b = blockIdx.y, oc = blockIdx.z;
  const int obase = oc*OCH;
  for (int i = tid; i < OCH*DC; i += 256) wo[i] = out_w[obase*DC + i];
  if (tid < OCH) ob[tid] = out_b[obase + tid];
  __syncthreads();
  const int t = tb*T3TILE + tid*2;
  float zx[DC], zy[DC];
  #pragma unroll
  for (int c = 0; c < DC; ++c) {
    const float2 v = *(const float2*)&zq[((size_t)b*DC + c)*TT + t];
    zx[c] = v.x; zy[c] = v.y;
  }
  float* op = dout + ((size_t)b*DIN + obase)*TT + t;
  #pragma unroll 4
  for (int o = 0; o < OCH; ++o) {
    const float4 w0 = *(const float4*)&wo[o*DC];
    const float4 w1 = *(const float4*)&wo[o*DC+4];
    const float bv = ob[o];
    float s0 = bv, s1 = bv;
    s0 = fmaf(zx[0], w0.x, s0);  s1 = fmaf(zy[0], w0.x, s1);
    s0 = fmaf(zx[1], w0.y, s0);  s1 = fmaf(zy[1], w0.y, s1);
    s0 = fmaf(zx[2], w0.z, s0);  s1 = fmaf(zy[2], w0.z, s1);
    s0 = fmaf(zx[3], w0.w, s0);  s1 = fmaf(zy[3], w0.w, s1);
    s0 = fmaf(zx[4], w1.x, s0);  s1 = fmaf(zy[4], w1.x, s1);
    s0 = fmaf(zx[5], w1.y, s0);  s1 = fmaf(zy[5], w1.y, s1);
    s0 = fmaf(zx[6], w1.z, s0);  s1 = fmaf(zy[6], w1.z, s1);
    s0 = fmaf(zx[7], w1.w, s0);  s1 = fmaf(zy[7], w1.w, s1);
    *(float2*)&op[(size_t)o*TT] = make_float2(s0, s1);
  }
  // loss finalize tail: one thread per b (lpart written by KB, prior kernel)
  if (tb == 0 && oc == 0 && tid == 0) {
    float s = 0.f;
    for (int j = 0; j < NTA; ++j) s += lpart[b*NTA + j];
    const float v = s / (float)(TT*DC);
    dout[OFF_CL + b] = v;
    dout[OFF_CB + b] = v;
  }
}

extern "C" void kernel_launch(void* const* d_in, const int* in_sizes, int n_in,
                              void* d_out, int out_size, void* d_ws, size_t ws_size,
                              hipStream_t stream) {
  const float* z     = (const float*)d_in[0];
  const float* in_w  = (const float*)d_in[1];
  const float* in_b  = (const float*)d_in[2];
  const float* out_w = (const float*)d_in[3];
  const float* out_b = (const float*)d_in[4];
  const float* cbk   = (const float*)d_in[5];
  float* out = (float*)d_out;
  float* ws  = (float*)d_ws;
  const float* ze = out + OFF_ZE;

  float* ZQ = ws;                       // 524,288 floats
  float* LP = ZQ + (size_t)NB*DC*TT;    // 512 floats

  vq_kA<<<dim3(NTA, NB),              512, 0, stream>>>(z, in_w, in_b, out);
  vq_kB<<<dim3(NTA, NB),              512, 0, stream>>>(ze, cbk, out, ZQ, LP);
  vq_kC<<<dim3(TT/T3TILE, NB, NOC),   256, 0, stream>>>(ZQ, out_w, out_b, LP, out);
}

// Round 10
// 140.118 us; speedup vs baseline: 7.7969x; 1.1486x over previous
//
#include <hip/hip_runtime.h>
#include <math.h>

#define NB   16
#define DIN  1024
#define TT   4096
#define DC   8
#define NK   1024
#define TA   128
#define NTA  (TT/TA)      // 32
#define NPG  16
#define KCP  (NK/NPG)     // 64

// d_out offsets (floats), in reference return order
#define OFF_CL  ((size_t)NB*DIN*TT)
#define OFF_CB  (OFF_CL + NB)
#define OFF_IDX (OFF_CB + NB)
#define OFF_ZE  (OFF_IDX + (size_t)NB*TT)

// ---------------- MEGA: in_proj -> VQ -> rotation -> out_proj, one block per (b, t-tile) ----------------
__global__ __launch_bounds__(512, 4) void vq_mega(const float* __restrict__ z,
    const float* __restrict__ in_w, const float* __restrict__ in_b,
    const float* __restrict__ out_w, const float* __restrict__ out_b,
    const float* __restrict__ cbk, float* __restrict__ dout,
    float* __restrict__ lpart)
{
  __shared__ float regA[DIN*DC];   // 32 KB: wt[d][o] -> cn[k][i] -> wo[o][c]
  __shared__ float regB[4*TA*DC];  // 16 KB: pacc[sub][t][o] -> cand[pg][t] (float2)
  __shared__ float ze_s[DC*TA];    //  4 KB [o][t]
  __shared__ float zq_s[DC*TA];    //  4 KB [c][t]
  __shared__ float cn2[NK];        //  4 KB
  __shared__ float obs[DIN];       //  4 KB
  __shared__ float lred[TA];       // 512 B

  const int tid = threadIdx.x;
  const int tb = blockIdx.x, b = blockIdx.y;
  const int t0 = tb*TA;

  // ======== P1: in_proj (round-9 KA verbatim) ========
  for (int i = tid; i < DIN*DC; i += 512) {
    const int d = i >> 3, o = i & 7;
    regA[i] = in_w[o*DIN + d];
  }
  __syncthreads();
  const int sub = tid >> 7, tl = tid & 127;
  {
    const int dbase = sub*256;
    const float* zp = z + ((size_t)b*DIN + dbase)*TT + t0 + tl;
    float acc[DC];
    #pragma unroll
    for (int o = 0; o < DC; ++o) acc[o] = 0.f;
    #pragma unroll 8
    for (int d = 0; d < 256; ++d) {
      const float v = zp[(size_t)d*TT];
      const float4 w0 = *(const float4*)&regA[(dbase+d)*DC];
      const float4 w1 = *(const float4*)&regA[(dbase+d)*DC+4];
      acc[0] = fmaf(v, w0.x, acc[0]);
      acc[1] = fmaf(v, w0.y, acc[1]);
      acc[2] = fmaf(v, w0.z, acc[2]);
      acc[3] = fmaf(v, w0.w, acc[3]);
      acc[4] = fmaf(v, w1.x, acc[4]);
      acc[5] = fmaf(v, w1.y, acc[5]);
      acc[6] = fmaf(v, w1.z, acc[6]);
      acc[7] = fmaf(v, w1.w, acc[7]);
    }
    float* pa = &regB[(sub*TA + tl)*DC];
    *(float4*)&pa[0] = make_float4(acc[0], acc[1], acc[2], acc[3]);
    *(float4*)&pa[4] = make_float4(acc[4], acc[5], acc[6], acc[7]);
  }
  __syncthreads();
  #pragma unroll
  for (int oo = 0; oo < 2; ++oo) {
    const int o = sub + oo*4;
    float s = regB[(0*TA + tl)*DC + o];
    s += regB[(1*TA + tl)*DC + o];
    s += regB[(2*TA + tl)*DC + o];
    s += regB[(3*TA + tl)*DC + o];
    const float v = s + in_b[o];
    ze_s[o*TA + tl] = v;
    dout[OFF_ZE + ((size_t)b*DC + o)*TT + t0 + tl] = v;
  }
  __syncthreads();

  // ======== P2: stage+normalize codebook into regA (round-1 chain) ========
  for (int k = tid; k < NK; k += 512) {
    float c[DC];
    const float4 c0 = *(const float4*)&cbk[k*DC];
    const float4 c1 = *(const float4*)&cbk[k*DC+4];
    c[0]=c0.x; c[1]=c0.y; c[2]=c0.z; c[3]=c0.w;
    c[4]=c1.x; c[5]=c1.y; c[6]=c1.z; c[7]=c1.w;
    float ss = 0.f;
    #pragma unroll
    for (int i = 0; i < DC; ++i) ss = fmaf(c[i], c[i], ss);
    const float den = fmaxf(sqrtf(ss), 1e-12f);
    float s2 = 0.f;
    #pragma unroll
    for (int i = 0; i < DC; ++i) { const float v = c[i]/den; regA[k*DC+i] = v; s2 = fmaf(v, v, s2); }
    cn2[k] = s2;
  }
  __syncthreads();

  // scan: 16 partitions x 32 lanes, 4 t/thread (round-9 KB verbatim)
  {
    const int pg = tid >> 5, l = tid & 31;
    const int k0 = pg*KCP;
    float en[4][DC], en2v[4];
    #pragma unroll
    for (int m = 0; m < 4; ++m) {
      const int t = l + 32*m;
      float e[DC];
      #pragma unroll
      for (int o = 0; o < DC; ++o) e[o] = ze_s[o*TA + t];
      float se = 0.f;
      #pragma unroll
      for (int i = 0; i < DC; ++i) se = fmaf(e[i], e[i], se);
      const float dene = fmaxf(sqrtf(se), 1e-12f);
      float s2 = 0.f;
      #pragma unroll
      for (int i = 0; i < DC; ++i) { en[m][i] = e[i]/dene; s2 = fmaf(en[m][i], en[m][i], s2); }
      en2v[m] = s2;
    }
    float bd[4]; int bk[4];
    #pragma unroll
    for (int m = 0; m < 4; ++m) { bd[m] = 3.4e38f; bk[m] = k0; }
    #pragma unroll 2
    for (int k = 0; k < KCP; ++k) {
      const float4 a0 = *(const float4*)&regA[(k0+k)*DC];
      const float4 a1 = *(const float4*)&regA[(k0+k)*DC+4];
      const float c2 = cn2[k0+k];
      #pragma unroll
      for (int m = 0; m < 4; ++m) {
        float dacc = en[m][0]*a0.x;
        dacc = fmaf(en[m][1], a0.y, dacc);
        dacc = fmaf(en[m][2], a0.z, dacc);
        dacc = fmaf(en[m][3], a0.w, dacc);
        dacc = fmaf(en[m][4], a1.x, dacc);
        dacc = fmaf(en[m][5], a1.y, dacc);
        dacc = fmaf(en[m][6], a1.z, dacc);
        dacc = fmaf(en[m][7], a1.w, dacc);
        const float dist = (en2v[m] - 2.0f*dacc) + c2;   // exact round-1 chain
        if (dist < bd[m]) { bd[m] = dist; bk[m] = k0 + k; }
      }
    }
    float2* cand = (float2*)regB;   // pacc dead; cand[pg][t]
    #pragma unroll
    for (int m = 0; m < 4; ++m)
      cand[pg*TA + l + 32*m] = make_float2(bd[m], __int_as_float(bk[m]));
  }
  __syncthreads();

  // merge + rotation (lanes < 128) overlapped with out_w staging (lanes >= 128)
  if (tid < TA) {
    const float2* cand = (const float2*)regB;
    float bdm = cand[tid].x;
    int bkm = __float_as_int(cand[tid].y);
    #pragma unroll
    for (int p = 1; p < NPG; ++p) {
      const float2 c = cand[p*TA + tid];
      if (c.x < bdm) { bdm = c.x; bkm = __float_as_int(c.y); }   // ascending p => first occurrence
    }
    dout[OFF_IDX + (size_t)b*TT + t0 + tid] = (float)bkm;

    float e[DC], en_[DC];
    #pragma unroll
    for (int o = 0; o < DC; ++o) e[o] = ze_s[o*TA + tid];
    float se = 0.f;
    #pragma unroll
    for (int i = 0; i < DC; ++i) se = fmaf(e[i], e[i], se);
    const float ne = sqrtf(se);
    const float dene = fmaxf(ne, 1e-12f);
    #pragma unroll
    for (int i = 0; i < DC; ++i) en_[i] = e[i]/dene;

    float q[DC];
    {
      const float4 q0 = *(const float4*)&cbk[bkm*DC];
      const float4 q1 = *(const float4*)&cbk[bkm*DC+4];
      q[0]=q0.x; q[1]=q0.y; q[2]=q0.z; q[3]=q0.w;
      q[4]=q1.x; q[5]=q1.y; q[6]=q1.z; q[7]=q1.w;
    }
    float cl = 0.f;
    #pragma unroll
    for (int i = 0; i < DC; ++i) { const float d = e[i]-q[i]; cl = fmaf(d, d, cl); }

    float sq = 0.f;
    #pragma unroll
    for (int i = 0; i < DC; ++i) sq = fmaf(q[i], q[i], sq);
    const float nq = sqrtf(sq);
    const float denq = fmaxf(nq, 1e-12f);
    float qn[DC], rr[DC];
    float sr = 0.f;
    #pragma unroll
    for (int i = 0; i < DC; ++i) { qn[i] = q[i]/denq; rr[i] = en_[i]+qn[i]; sr = fmaf(rr[i], rr[i], sr); }
    const float denr = fmaxf(sqrtf(sr), 1e-12f);
    float r_[DC];
    float rdz = 0.f, edz = 0.f;
    #pragma unroll
    for (int i = 0; i < DC; ++i) { r_[i] = rr[i]/denr; rdz = fmaf(r_[i], e[i], rdz); edz = fmaf(en_[i], e[i], edz); }
    const float scal = nq / fmaxf(ne, 1e-8f);
    #pragma unroll
    for (int i = 0; i < DC; ++i) {
      const float v = scal * ((e[i] - 2.0f*r_[i]*rdz) + 2.0f*qn[i]*edz);
      zq_s[i*TA + tid] = v;
    }
    lred[tid] = cl;
  } else {
    const int ti = tid - TA;   // 384 stagers
    for (int i = ti; i < DIN*DC; i += 512-TA) regA[i] = out_w[i];
    for (int i = ti; i < DIN; i += 512-TA) obs[i] = out_b[i];
  }
  __syncthreads();
  for (int s = TA/2; s > 0; s >>= 1) {
    if (tid < s) lred[tid] += lred[tid + s];
    __syncthreads();
  }
  if (tid == 0) lpart[b*NTA + tb] = lred[0];

  // ======== P3: out_proj (round-8 KC chain verbatim; wo reads are wave-uniform broadcasts) ========
  {
    const int sub3 = tid >> 6, tl2 = tid & 63;
    const int obase = sub3*128;
    const int tt2 = tl2*2;
    float zx[DC], zy[DC];
    #pragma unroll
    for (int c = 0; c < DC; ++c) {
      zx[c] = zq_s[c*TA + tt2];
      zy[c] = zq_s[c*TA + tt2 + 1];
    }
    float* op = dout + ((size_t)b*DIN + obase)*TT + t0 + tt2;
    #pragma unroll 4
    for (int o = 0; o < 128; ++o) {
      const float4 w0 = *(const float4*)&regA[(obase+o)*DC];
      const float4 w1 = *(const float4*)&regA[(obase+o)*DC+4];
      const float bv = obs[obase+o];
      float s0 = bv, s1 = bv;
      s0 = fmaf(zx[0], w0.x, s0);  s1 = fmaf(zy[0], w0.x, s1);
      s0 = fmaf(zx[1], w0.y, s0);  s1 = fmaf(zy[1], w0.y, s1);
      s0 = fmaf(zx[2], w0.z, s0);  s1 = fmaf(zy[2], w0.z, s1);
      s0 = fmaf(zx[3], w0.w, s0);  s1 = fmaf(zy[3], w0.w, s1);
      s0 = fmaf(zx[4], w1.x, s0);  s1 = fmaf(zy[4], w1.x, s1);
      s0 = fmaf(zx[5], w1.y, s0);  s1 = fmaf(zy[5], w1.y, s1);
      s0 = fmaf(zx[6], w1.z, s0);  s1 = fmaf(zy[6], w1.z, s1);
      s0 = fmaf(zx[7], w1.w, s0);  s1 = fmaf(zy[7], w1.w, s1);
      *(float2*)&op[(size_t)o*TT] = make_float2(s0, s1);
    }
  }
}

// ---------------- finalize: losses (idempotent) ----------------
__global__ void vq_fin(const float* __restrict__ lpart, float* __restrict__ dout)
{
  const int b = threadIdx.x;
  if (b < NB) {
    float s = 0.f;
    for (int j = 0; j < NTA; ++j) s += lpart[b*NTA + j];
    const float v = s / (float)(TT*DC);
    dout[OFF_CL + b] = v;
    dout[OFF_CB + b] = v;
  }
}

extern "C" void kernel_launch(void* const* d_in, const int* in_sizes, int n_in,
                              void* d_out, int out_size, void* d_ws, size_t ws_size,
                              hipStream_t stream) {
  const float* z     = (const float*)d_in[0];
  const float* in_w  = (const float*)d_in[1];
  const float* in_b  = (const float*)d_in[2];
  const float* out_w = (const float*)d_in[3];
  const float* out_b = (const float*)d_in[4];
  const float* cbk   = (const float*)d_in[5];
  float* out = (float*)d_out;
  float* LP  = (float*)d_ws;   // NB*NTA = 512 floats

  vq_mega<<<dim3(NTA, NB), 512, 0, stream>>>(z, in_w, in_b, out_w, out_b, cbk, out, LP);
  vq_fin <<<1, 256, 0, stream>>>(LP, out);
}